// Round 10
// baseline (190.735 us; speedup 1.0000x reference)
//
#include <hip/hip_runtime.h>
#include <hip/hip_bf16.h>

// Problem constants
#define DIM   1024
#define NHEAD 16
#define HDIM  64
#define BATCH 2
#define SEQ   2048
#define TOK   (BATCH*SEQ)          // 4096
#define ROWS  (BATCH*NHEAD*SEQ)    // 65536 (bh*SEQ+q rows)
// q pre-scale: 64^-0.5 * log2(e)  (exp(s) == exp2(s*log2e), folded into Q)
#define QSCALE 0.1803368801111204f

typedef unsigned short u16;
typedef __attribute__((ext_vector_type(8))) _Float16 h16x8;   // 8 fp16 (4 VGPRs)
typedef __attribute__((ext_vector_type(2))) __fp16 fp16x2;    // cvt_pkrtz result
typedef __attribute__((ext_vector_type(4))) float f32x4;      // 16x16 C/D
typedef __attribute__((ext_vector_type(16))) float f32x16;    // 32x32 C/D
typedef __attribute__((ext_vector_type(2))) int i32x2;        // permlane32_swap result

__device__ __forceinline__ u16 f2h(float f) {
    union { _Float16 h; u16 u; } v; v.h = (_Float16)f;        // v_cvt_f16_f32 (RNE)
    return v.u;
}
__device__ __forceinline__ unsigned pack2h(float a, float b) {
    return (unsigned)f2h(a) | ((unsigned)f2h(b) << 16);
}
__device__ __forceinline__ unsigned pkrtz(float a, float b) { // 1 VALU op
    union { fp16x2 h; unsigned u; } v;
    v.h = __builtin_amdgcn_cvt_pkrtz(a, b);
    return v.u;
}
__device__ __forceinline__ f32x16 zero16() {
    f32x16 v;
#pragma unroll
    for (int i = 0; i < 16; ++i) v[i] = 0.f;
    return v;
}

typedef __attribute__((address_space(3))) void lds_void;
typedef const __attribute__((address_space(1))) void gbl_void;
__device__ __forceinline__ void gload_lds16(const void* g, void* l) {
    __builtin_amdgcn_global_load_lds((gbl_void*)g, (lds_void*)l, 16, 0, 0);
}

// ---------------------------------------------------------------------------
// Fused converts (single launch).
//   blocks [0, 4096):        x fp32 -> xh fp16 (vectorized copy-cast)
//   blocks [4096, 7168):     wqkv [1024][3072] -> wqT [3072][1024] fp16 (T)
//   blocks [7168, 8192):     wo   [1024][1024] -> woT [1024][1024] fp16 (T)
// ---------------------------------------------------------------------------
__global__ __launch_bounds__(256)
void fused_cvt(const float* __restrict__ x,    u16* __restrict__ xh,
               const float* __restrict__ wqkv, u16* __restrict__ wqT,
               const float* __restrict__ wo,   u16* __restrict__ woT) {
    __shared__ float t[32][33];
    const int bid = blockIdx.x;
    if (bid < 4096) {                   // plain cast path
        int i = bid * 256 + threadIdx.x;              // float4 index
        float4 v = ((const float4*)x)[i];
        ((uint2*)xh)[i] = make_uint2(pack2h(v.x, v.y), pack2h(v.z, v.w));
        return;
    }
    // transpose paths
    const float* in; u16* outT; int K, N, tb;
    if (bid < 7168) { in = wqkv; outT = wqT; K = 1024; N = 3072; tb = bid - 4096; }
    else            { in = wo;   outT = woT; K = 1024; N = 1024; tb = bid - 7168; }
    const int nbx = N / 32;
    const int n0 = (tb % nbx) * 32, k0 = (tb / nbx) * 32;
    const int tx = threadIdx.x & 31, ty = threadIdx.x >> 5;
#pragma unroll
    for (int i = 0; i < 4; ++i)
        t[ty + i * 8][tx] = in[(size_t)(k0 + ty + i * 8) * N + n0 + tx];
    __syncthreads();
#pragma unroll
    for (int i = 0; i < 4; ++i)
        outT[(size_t)(n0 + ty + i * 8) * K + k0 + tx] = f2h(t[tx][ty + i * 8]);
}

// ---------------------------------------------------------------------------
// QKV GEMM (fp16 MFMA, single-buffer 32 KB LDS).
// Epilogue per-head re-layout:
//   q (col<1024):        Qh[bh][s][d] = (acc+bias)*QSCALE  (fp16)
//   k (1024<=col<2048):  Kh[bh][s][d] = acc+bias
//   v (col>=2048):       Vh[bh][d][s] = acc+bias           (transposed)
// ---------------------------------------------------------------------------
__global__ __launch_bounds__(256)
void gemm_qkv(const u16* __restrict__ Ag, const u16* __restrict__ Bg,
              const float* __restrict__ bias, u16* __restrict__ Qh,
              u16* __restrict__ Kh, u16* __restrict__ Vh, int K, int N) {
    __shared__ u16 As[128 * 64];
    __shared__ u16 Bs[128 * 64];

    const int tid  = threadIdx.x;
    const int lane = tid & 63;
    const int w    = tid >> 6;
    const int c    = lane & 15;
    const int quad = lane >> 4;
    const int wm   = (w & 1) * 64;
    const int wn   = (w >> 1) * 64;
    const int row0 = blockIdx.y * 128;
    const int col0 = blockIdx.x * 128;
    const int sw   = c & 7;

    f32x4 acc[4][4];
#pragma unroll
    for (int m = 0; m < 4; ++m)
#pragma unroll
        for (int n = 0; n < 4; ++n) acc[m][n] = (f32x4){0.f, 0.f, 0.f, 0.f};

    for (int k0 = 0; k0 < K; k0 += 64) {
        __syncthreads();
#pragma unroll
        for (int i = 0; i < 4; ++i) {
            int idx = tid + i * 256;
            int r = idx >> 3, p = idx & 7;
            int g = p ^ (r & 7);
            gload_lds16(Ag + (size_t)(row0 + r) * K + k0 + g * 8, &As[idx * 8]);
            gload_lds16(Bg + (size_t)(col0 + r) * K + k0 + g * 8, &Bs[idx * 8]);
        }
        __syncthreads();

        h16x8 af[4][2];
#pragma unroll
        for (int m = 0; m < 4; ++m)
#pragma unroll
            for (int kh = 0; kh < 2; ++kh)
                af[m][kh] = *(const h16x8*)&As[(wm + m * 16 + c) * 64 +
                                              ((kh * 4 + quad) ^ sw) * 8];
#pragma unroll
        for (int kh = 0; kh < 2; ++kh)
#pragma unroll
            for (int n = 0; n < 4; ++n) {
                h16x8 bf = *(const h16x8*)&Bs[(wn + n * 16 + c) * 64 +
                                              ((kh * 4 + quad) ^ sw) * 8];
#pragma unroll
                for (int m = 0; m < 4; ++m)
                    acc[m][n] = __builtin_amdgcn_mfma_f32_16x16x32_f16(
                        af[m][kh], bf, acc[m][n], 0, 0, 0);
            }
    }

#pragma unroll
    for (int n = 0; n < 4; ++n) {
        const int col = col0 + wn + n * 16 + c;
        const float bv = bias[col];
        const int h = (col >> 6) & 15, d = col & 63;
#pragma unroll
        for (int m = 0; m < 4; ++m) {
            const int rbase = row0 + wm + m * 16 + quad * 4;
            const int b = rbase >> 11, s0 = rbase & (SEQ - 1);
            const int bh = (b << 4) + h;
            if (col0 < DIM) {
#pragma unroll
                for (int r = 0; r < 4; ++r)
                    Qh[((size_t)bh * SEQ + s0 + r) * 64 + d] =
                        f2h((acc[m][n][r] + bv) * QSCALE);
            } else if (col0 < 2 * DIM) {
#pragma unroll
                for (int r = 0; r < 4; ++r)
                    Kh[((size_t)bh * SEQ + s0 + r) * 64 + d] =
                        f2h(acc[m][n][r] + bv);
            } else {
                uint2 pv = make_uint2(pack2h(acc[m][n][0] + bv, acc[m][n][1] + bv),
                                      pack2h(acc[m][n][2] + bv, acc[m][n][3] + bv));
                *(uint2*)&Vh[((size_t)bh * 64 + d) * SEQ + s0] = pv;
            }
        }
    }
}

// ---------------------------------------------------------------------------
// Out-proj GEMM: C[M,N] = A[M,K] @ B[N,K]^T + bias, fp32 out. 128x128 tile,
// single-buffered (32 KB LDS). Per-output-element K order unchanged.
// ---------------------------------------------------------------------------
__global__ __launch_bounds__(256)
void gemm_out(const u16* __restrict__ Ag, const u16* __restrict__ Bg,
              const float* __restrict__ bias, float* __restrict__ Cout,
              int M, int N, int K) {
    __shared__ u16 As[128 * 64];
    __shared__ u16 Bs[128 * 64];

    const int tid  = threadIdx.x;
    const int lane = tid & 63;
    const int w    = tid >> 6;
    const int c    = lane & 15;
    const int quad = lane >> 4;
    const int wm   = (w & 1) * 64;
    const int wn   = (w >> 1) * 64;
    const int row0 = blockIdx.y * 128;
    const int col0 = blockIdx.x * 128;
    const int sw   = c & 7;

    f32x4 acc[4][4];
#pragma unroll
    for (int m = 0; m < 4; ++m)
#pragma unroll
        for (int n = 0; n < 4; ++n) acc[m][n] = (f32x4){0.f, 0.f, 0.f, 0.f};

    for (int k0 = 0; k0 < K; k0 += 64) {
        __syncthreads();
#pragma unroll
        for (int i = 0; i < 4; ++i) {
            int idx = tid + i * 256;
            int r = idx >> 3, p = idx & 7;
            int g = p ^ (r & 7);
            gload_lds16(Ag + (size_t)(row0 + r) * K + k0 + g * 8, &As[idx * 8]);
            gload_lds16(Bg + (size_t)(col0 + r) * K + k0 + g * 8, &Bs[idx * 8]);
        }
        __syncthreads();

        h16x8 af[4][2];
#pragma unroll
        for (int m = 0; m < 4; ++m)
#pragma unroll
            for (int kh = 0; kh < 2; ++kh)
                af[m][kh] = *(const h16x8*)&As[(wm + m * 16 + c) * 64 +
                                              ((kh * 4 + quad) ^ sw) * 8];
#pragma unroll
        for (int kh = 0; kh < 2; ++kh)
#pragma unroll
            for (int n = 0; n < 4; ++n) {
                h16x8 bf = *(const h16x8*)&Bs[(wn + n * 16 + c) * 64 +
                                              ((kh * 4 + quad) ^ sw) * 8];
#pragma unroll
                for (int m = 0; m < 4; ++m)
                    acc[m][n] = __builtin_amdgcn_mfma_f32_16x16x32_f16(
                        af[m][kh], bf, acc[m][n], 0, 0, 0);
            }
    }

#pragma unroll
    for (int n = 0; n < 4; ++n) {
        const int col = col0 + wn + n * 16 + c;
        const float bv = bias[col];
#pragma unroll
        for (int m = 0; m < 4; ++m) {
            const int rbase = row0 + wm + m * 16 + quad * 4;
#pragma unroll
            for (int r = 0; r < 4; ++r)
                Cout[(size_t)(rbase + r) * N + col] = acc[m][n][r] + bv;
        }
    }
}

// ---------------------------------------------------------------------------
// Flash attention v15: v14's structure + KEY-SPLIT ACROSS BLOCKS to fix the
// grid-limited occupancy v14 exposed (512 blocks = 2/CU; LDS shrink alone
// couldn't help). Grid (16 q-blocks, 32 bh, 2 key-splits) = 1024 blocks;
// each block processes 8 of 16 key-tiles and writes PARTIAL O (fp16,
// un-normalized, into d_out used as scratch) + partial l. 4 blocks/CU
// (4 x 33.8 KB LDS = 135 <= 160; 4 x 112 VGPR = 448 <= 512) -> 4 waves/SIMD
// of independent, anti-phase blocks: exp2/VALU overlaps MFMA cross-wave.
// attn_combine then computes (O0+O1)/(l0+l1) -> ao.
// Per-tile math bit-identical to v11/v14; new fp16 rounding of O partials
// (~5e-4 rel) + one fp32 reassociation -- far under the 5.4e-3 threshold.
// ---------------------------------------------------------------------------
__global__ __launch_bounds__(256, 2)
void flash_attn15(const u16* __restrict__ Qg, const u16* __restrict__ Kg,
                  const u16* __restrict__ Vg, u16* __restrict__ Op,
                  float* __restrict__ lp) {
    __shared__ u16 KV[2][64 * 128];     // [0]=Ks [key][d], [1]=Vt [d][key]
    __shared__ float lc[256];           // l-combine (1 KB)

    u16* Ks = KV[0];
    u16* Vt = KV[1];

    const int tid  = threadIdx.x;
    const int lane = tid & 63;
    const int w    = tid >> 6;          // 0..3
    const int wq   = w & 1;             // q-half (64 rows)
    const int wk   = w >> 1;            // key-half within the 128-tile
    const int n32  = lane & 31;         // q column within strip
    const int q5   = lane >> 5;         // 0/1
    const int bh   = blockIdx.y;
    const int ks   = blockIdx.z;        // key-split: tiles [ks*8, ks*8+8)
    const int q0   = blockIdx.x * 128;

    const u16* Qb = Qg + (size_t)bh * SEQ * 64;
    const u16* Kb = Kg + (size_t)bh * SEQ * 64;
    const u16* Vb = Vg + (size_t)bh * 64 * SEQ;

    const int qrowA = wq * 64 + n32;    // strip A q row (block-local)
    const int qrowB = qrowA + 32;       // strip B
    const int sw    = n32 & 7;          // == qrowA&7 == qrowB&7 == key/d-row&7

    // ---- Q fragments: direct global loads, loop-invariant (chunk (2s+q5)) --
    h16x8 qbA[4], qbB[4];
    {
        const u16* qa  = Qb + (size_t)(q0 + qrowA) * 64;
        const u16* qb_ = Qb + (size_t)(q0 + qrowB) * 64;
#pragma unroll
        for (int s = 0; s < 4; ++s) {
            qbA[s] = *(const h16x8*)&qa[(s * 2 + q5) * 8];
            qbB[s] = *(const h16x8*)&qb_[(s * 2 + q5) * 8];
        }
    }

    float lA = 0.f, lB = 0.f;
    f32x16 oA[2] = {zero16(), zero16()};  // O^T[d-tile][q], strip A (wk half)
    f32x16 oB[2] = {zero16(), zero16()};  // strip B

    for (int it = 0; it < 8; ++it) {
        const int k1 = (ks * 8 + it) * 128;

        if (it) __syncthreads();        // prev readers done -> safe to overwrite

        // ---- stage this 128-key tile (single buffer) ----
#pragma unroll
        for (int i = 0; i < 4; ++i) {
            int idx = tid + i * 256;
            int rk = idx >> 3, pk = idx & 7, gk = pk ^ (rk & 7);
            gload_lds16(Kb + (size_t)(k1 + rk) * 64 + gk * 8, &Ks[idx * 8]);
            int rv = idx >> 4, cv = idx & 15, gv = cv ^ (rv & 7);
            gload_lds16(Vb + (size_t)rv * SEQ + k1 + gv * 8, &Vt[idx * 8]);
        }
        __syncthreads();                // loads drained (vmcnt0 at barrier)

        // ---- this wave's 64-key subtile x 64 q-rows, P in registers ----
        unsigned xwA[8][2], xwB[8][2];  // packed fp16 P, chunk-major
#pragma unroll
        for (int sub = 0; sub < 2; ++sub) {
            const int kr = wk * 64 + sub * 32 + n32;   // kr&7 == sw
            f32x16 saA = zero16(), saB = zero16();
            __builtin_amdgcn_s_setprio(1);
#pragma unroll
            for (int s = 0; s < 4; ++s) {
                h16x8 ak = *(const h16x8*)&Ks[kr * 64 +
                                              (((s * 2 + q5) ^ sw) * 8)];
                saA = __builtin_amdgcn_mfma_f32_32x32x16_f16(ak, qbA[s], saA, 0, 0, 0);
                saB = __builtin_amdgcn_mfma_f32_32x32x16_f16(ak, qbB[s], saB, 0, 0, 0);
            }
            __builtin_amdgcn_s_setprio(0);
#pragma unroll
            for (int rr = 0; rr < 4; ++rr) {
                float a0 = __builtin_amdgcn_exp2f(saA[4 * rr + 0]);
                float a1 = __builtin_amdgcn_exp2f(saA[4 * rr + 1]);
                float a2 = __builtin_amdgcn_exp2f(saA[4 * rr + 2]);
                float a3 = __builtin_amdgcn_exp2f(saA[4 * rr + 3]);
                lA += (a0 + a1) + (a2 + a3);
                xwA[sub * 4 + rr][0] = pkrtz(a0, a1);
                xwA[sub * 4 + rr][1] = pkrtz(a2, a3);
                float b0 = __builtin_amdgcn_exp2f(saB[4 * rr + 0]);
                float b1 = __builtin_amdgcn_exp2f(saB[4 * rr + 1]);
                float b2 = __builtin_amdgcn_exp2f(saB[4 * rr + 2]);
                float b3 = __builtin_amdgcn_exp2f(saB[4 * rr + 3]);
                lB += (b0 + b1) + (b2 + b3);
                xwB[sub * 4 + rr][0] = pkrtz(b0, b1);
                xwB[sub * 4 + rr][1] = pkrtz(b2, b3);
            }
        }

        // ---- P^T B-frags via permlane32_swap (no LDS round trip) ----
        h16x8 bpA[4], bpB[4];
#pragma unroll
        for (int s = 0; s < 4; ++s) {
            i32x2 ra = __builtin_amdgcn_permlane32_swap(
                (int)xwA[2 * s][0], (int)xwA[2 * s + 1][0], false, false);
            i32x2 rb = __builtin_amdgcn_permlane32_swap(
                (int)xwA[2 * s][1], (int)xwA[2 * s + 1][1], false, false);
            union { int u[4]; h16x8 h; } fa;
            fa.u[0] = ra[0]; fa.u[1] = rb[0]; fa.u[2] = ra[1]; fa.u[3] = rb[1];
            bpA[s] = fa.h;
            i32x2 rc = __builtin_amdgcn_permlane32_swap(
                (int)xwB[2 * s][0], (int)xwB[2 * s + 1][0], false, false);
            i32x2 rd = __builtin_amdgcn_permlane32_swap(
                (int)xwB[2 * s][1], (int)xwB[2 * s + 1][1], false, false);
            union { int u[4]; h16x8 h; } fb;
            fb.u[0] = rc[0]; fb.u[1] = rd[0]; fb.u[2] = rc[1]; fb.u[3] = rd[1];
            bpB[s] = fb.h;
        }

        // O^T += V^T P^T  (V columns of this wave's key-half; av shared)
        __builtin_amdgcn_s_setprio(1);
#pragma unroll
        for (int dt = 0; dt < 2; ++dt) {
            const int dr = dt * 32 + n32;       // dr&7 == sw
#pragma unroll
            for (int s = 0; s < 4; ++s) {
                h16x8 av = *(const h16x8*)&Vt[dr * 128 +
                                              ((wk * 8 + ((s * 2 + q5) ^ sw)) * 8)];
                oA[dt] = __builtin_amdgcn_mfma_f32_32x32x16_f16(av, bpA[s], oA[dt], 0, 0, 0);
                oB[dt] = __builtin_amdgcn_mfma_f32_32x32x16_f16(av, bpB[s], oB[dt], 0, 0, 0);
            }
        }
        __builtin_amdgcn_s_setprio(0);
    }
    __syncthreads();                    // all readers done before oc overlay

    // ---- merge q5 halves (intra-wave), then wk halves (cross-wave) ----
    lA += __shfl_xor(lA, 32, 64);
    lB += __shfl_xor(lB, 32, 64);

    float* oc = (float*)KV;             // 8192 floats (32 KB), dead K/V buffer
    const int rowA = (wq * 2 + 0) * 64 + lane;    // per-thread slot, strip A
    const int rowB = (wq * 2 + 1) * 64 + lane;    // strip B (256 rows x 32 fl)
    if (wk == 1) {
#pragma unroll
        for (int dt = 0; dt < 2; ++dt)
#pragma unroll
            for (int i = 0; i < 16; ++i) {
                oc[rowA * 32 + ((dt * 16 + i + lane) & 31)] = oA[dt][i];
                oc[rowB * 32 + ((dt * 16 + i + lane) & 31)] = oB[dt][i];
            }
        lc[rowA] = lA;
        lc[rowB] = lB;
    }
    __syncthreads();
    if (wk == 1) return;
    lA += lc[rowA];
    lB += lc[rowB];
#pragma unroll
    for (int dt = 0; dt < 2; ++dt)
#pragma unroll
        for (int i = 0; i < 16; ++i) {
            oA[dt][i] += oc[rowA * 32 + ((dt * 16 + i + lane) & 31)];
            oB[dt][i] += oc[rowB * 32 + ((dt * 16 + i + lane) & 31)];
        }

    // ---- write PARTIAL O (fp16, un-normalized) + partial l ----
    const size_t prow = (size_t)(ks * (BATCH * NHEAD) + bh) * SEQ + q0;
    if (q5 == 0) {                      // both q5 lanes hold the same l
        lp[prow + qrowA] = lA;
        lp[prow + qrowB] = lB;
    }
    u16* opA = Op + (prow + qrowA) * 64;
    u16* opB = Op + (prow + qrowB) * 64;
#pragma unroll
    for (int dt = 0; dt < 2; ++dt) {
#pragma unroll
        for (int rq = 0; rq < 4; ++rq) {
            const int d = dt * 32 + 8 * rq + 4 * q5;
            *(uint2*)&opA[d] = make_uint2(
                pkrtz(oA[dt][4 * rq + 0], oA[dt][4 * rq + 1]),
                pkrtz(oA[dt][4 * rq + 2], oA[dt][4 * rq + 3]));
            *(uint2*)&opB[d] = make_uint2(
                pkrtz(oB[dt][4 * rq + 0], oB[dt][4 * rq + 1]),
                pkrtz(oB[dt][4 * rq + 2], oB[dt][4 * rq + 3]));
        }
    }
}

// ---------------------------------------------------------------------------
// Combine the two key-split partials: ao = (O0 + O1) / (l0 + l1), with the
// per-head re-layout into [token][DIM]. 8 threads per (bh,q) row, 8 d each.
// ---------------------------------------------------------------------------
__global__ __launch_bounds__(256)
void attn_combine(const u16* __restrict__ Op, const float* __restrict__ lp,
                  u16* __restrict__ ao) {
    const int t   = blockIdx.x * 256 + threadIdx.x;
    const int row = t >> 3;                      // bh*SEQ + q  (65536 rows)
    const int d0  = (t & 7) * 8;
    const float inv = 1.f / (lp[row] + lp[ROWS + row]);
    union { uint4 u; _Float16 h[8]; } a, b;
    a.u = *(const uint4*)&Op[(size_t)row * 64 + d0];
    b.u = *(const uint4*)&Op[((size_t)ROWS + row) * 64 + d0];
    float s[8];
#pragma unroll
    for (int j = 0; j < 8; ++j) s[j] = ((float)a.h[j] + (float)b.h[j]) * inv;
    uint4 o = make_uint4(pkrtz(s[0], s[1]), pkrtz(s[2], s[3]),
                         pkrtz(s[4], s[5]), pkrtz(s[6], s[7]));
    const int bh = row >> 11, q = row & (SEQ - 1);
    const int bb = bh >> 4, h = bh & 15;
    *(uint4*)&ao[(size_t)(bb * SEQ + q) * DIM + h * HDIM + d0] = o;
}

// ---------------------------------------------------------------------------
extern "C" void kernel_launch(void* const* d_in, const int* in_sizes, int n_in,
                              void* d_out, int out_size, void* d_ws, size_t ws_size,
                              hipStream_t stream) {
    (void)in_sizes; (void)n_in; (void)out_size; (void)ws_size;
    const float* x    = (const float*)d_in[0];   // [4096,1024]
    const float* wqkv = (const float*)d_in[1];   // [1024,3072]
    const float* bqkv = (const float*)d_in[2];   // [3072]
    const float* wo   = (const float*)d_in[3];   // [1024,1024]
    const float* bo   = (const float*)d_in[4];   // [1024]
    float* out = (float*)d_out;                  // [4096,1024] fp32

    // workspace (48 MB)
    const size_t HB = (size_t)BATCH * NHEAD * SEQ * HDIM;   // 4M elems
    u16* Qh  = (u16*)d_ws;                       // [32][2048][64]
    u16* Kh  = Qh + HB;                          // [32][2048][64]
    u16* Vh  = Kh + HB;                          // [32][64][2048]
    u16* ao  = Vh + HB;                          // attn out fp16 [4096][1024]
    u16* wqT = ao + (size_t)TOK * DIM;           // wqkv^T fp16 [3072][1024]
    u16* woT = wqT + (size_t)3 * DIM * DIM;      // wo^T fp16 [1024][1024]
    u16* xh  = woT + (size_t)DIM * DIM;          // x fp16 [4096][1024]

    // scratch overlays (dead regions at attn time):
    u16*   Opart = (u16*)d_out;                  // 2x[32][2048][64] fp16 = 16 MB
    float* lpart = (float*)xh;                   // 2x[32][2048] fp32 = 512 KB
    // (xh is dead after gemm_qkv; d_out is rewritten in full by gemm_out)

    // 1) fused converts (single launch)
    fused_cvt<<<8192, 256, 0, stream>>>(x, xh, wqkv, wqT, wo, woT);
    // 2) qkv GEMM with per-head re-layout epilogue
    gemm_qkv<<<dim3(3 * DIM / 128, TOK / 128), 256, 0, stream>>>(
        xh, wqT, bqkv, Qh, Kh, Vh, DIM, 3 * DIM);
    // 3) attention partials (key-split x2 -> 1024 blocks -> 4 blocks/CU)
    flash_attn15<<<dim3(SEQ / 128, BATCH * NHEAD, 2), 256, 0, stream>>>(
        Qh, Kh, Vh, Opart, lpart);
    // 3b) combine partials -> ao
    attn_combine<<<ROWS * 8 / 256, 256, 0, stream>>>(Opart, lpart, ao);
    // 4) out = attn @ wo + bo (fp32 out, 128x128 single-buffer tile)
    gemm_out<<<dim3(DIM / 128, TOK / 128), 256, 0, stream>>>(
        ao, woT, bo, out, TOK, DIM, DIM);
}

// Round 11
// 176.660 us; speedup vs baseline: 1.0797x; 1.0797x over previous
//
#include <hip/hip_runtime.h>
#include <hip/hip_bf16.h>

// Problem constants
#define DIM   1024
#define NHEAD 16
#define HDIM  64
#define BATCH 2
#define SEQ   2048
#define TOK   (BATCH*SEQ)          // 4096
// q pre-scale: 64^-0.5 * log2(e)  (exp(s) == exp2(s*log2e), folded into Q)
#define QSCALE 0.1803368801111204f

typedef unsigned short u16;
typedef __attribute__((ext_vector_type(8))) _Float16 h16x8;   // 8 fp16 (4 VGPRs)
typedef __attribute__((ext_vector_type(2))) __fp16 fp16x2;    // cvt_pkrtz result
typedef __attribute__((ext_vector_type(4))) float f32x4;      // 16x16 C/D
typedef __attribute__((ext_vector_type(16))) float f32x16;    // 32x32 C/D
typedef __attribute__((ext_vector_type(2))) int i32x2;        // permlane32_swap result

__device__ __forceinline__ u16 f2h(float f) {
    union { _Float16 h; u16 u; } v; v.h = (_Float16)f;        // v_cvt_f16_f32 (RNE)
    return v.u;
}
__device__ __forceinline__ unsigned pack2h(float a, float b) {
    return (unsigned)f2h(a) | ((unsigned)f2h(b) << 16);
}
__device__ __forceinline__ unsigned pkrtz(float a, float b) { // 1 VALU op
    union { fp16x2 h; unsigned u; } v;
    v.h = __builtin_amdgcn_cvt_pkrtz(a, b);
    return v.u;
}
__device__ __forceinline__ f32x16 zero16() {
    f32x16 v;
#pragma unroll
    for (int i = 0; i < 16; ++i) v[i] = 0.f;
    return v;
}

typedef __attribute__((address_space(3))) void lds_void;
typedef const __attribute__((address_space(1))) void gbl_void;
__device__ __forceinline__ void gload_lds16(const void* g, void* l) {
    __builtin_amdgcn_global_load_lds((gbl_void*)g, (lds_void*)l, 16, 0, 0);
}

// ---------------------------------------------------------------------------
// Fused converts (single launch).
//   blocks [0, 4096):        x fp32 -> xh fp16 (vectorized copy-cast)
//   blocks [4096, 7168):     wqkv [1024][3072] -> wqT [3072][1024] fp16 (T)
//   blocks [7168, 8192):     wo   [1024][1024] -> woT [1024][1024] fp16 (T)
// ---------------------------------------------------------------------------
__global__ __launch_bounds__(256)
void fused_cvt(const float* __restrict__ x,    u16* __restrict__ xh,
               const float* __restrict__ wqkv, u16* __restrict__ wqT,
               const float* __restrict__ wo,   u16* __restrict__ woT) {
    __shared__ float t[32][33];
    const int bid = blockIdx.x;
    if (bid < 4096) {                   // plain cast path
        int i = bid * 256 + threadIdx.x;              // float4 index
        float4 v = ((const float4*)x)[i];
        ((uint2*)xh)[i] = make_uint2(pack2h(v.x, v.y), pack2h(v.z, v.w));
        return;
    }
    // transpose paths
    const float* in; u16* outT; int K, N, tb;
    if (bid < 7168) { in = wqkv; outT = wqT; K = 1024; N = 3072; tb = bid - 4096; }
    else            { in = wo;   outT = woT; K = 1024; N = 1024; tb = bid - 7168; }
    const int nbx = N / 32;
    const int n0 = (tb % nbx) * 32, k0 = (tb / nbx) * 32;
    const int tx = threadIdx.x & 31, ty = threadIdx.x >> 5;
#pragma unroll
    for (int i = 0; i < 4; ++i)
        t[ty + i * 8][tx] = in[(size_t)(k0 + ty + i * 8) * N + n0 + tx];
    __syncthreads();
#pragma unroll
    for (int i = 0; i < 4; ++i)
        outT[(size_t)(n0 + ty + i * 8) * K + k0 + tx] = f2h(t[tx][ty + i * 8]);
}

// ---------------------------------------------------------------------------
// QKV GEMM (fp16 MFMA). 512 threads = 8 waves (4x2 wave grid, 32x64/wave):
// per-wave MFMA work halves vs the 256-thread version and waves/SIMD go
// 3 -> 6 (768 blocks = 3/CU x 8 waves), hiding ds_read->MFMA and staging
// latency via TLP at unchanged 32 KB LDS. Per-output-element K-accumulation
// order identical to the 256-thread version -> bitwise-identical results.
// Epilogue per-head re-layout:
//   q (col<1024):        Qh[bh][s][d] = (acc+bias)*QSCALE  (fp16)
//   k (1024<=col<2048):  Kh[bh][s][d] = acc+bias
//   v (col>=2048):       Vh[bh][d][s] = acc+bias           (transposed)
// ---------------------------------------------------------------------------
__global__ __launch_bounds__(512)
void gemm_qkv(const u16* __restrict__ Ag, const u16* __restrict__ Bg,
              const float* __restrict__ bias, u16* __restrict__ Qh,
              u16* __restrict__ Kh, u16* __restrict__ Vh, int K, int N) {
    __shared__ u16 As[128 * 64];
    __shared__ u16 Bs[128 * 64];

    const int tid  = threadIdx.x;
    const int lane = tid & 63;
    const int w    = tid >> 6;          // 0..7
    const int c    = lane & 15;
    const int quad = lane >> 4;
    const int wm   = (w & 3) * 32;      // 4 wave-rows
    const int wn   = (w >> 2) * 64;     // 2 wave-cols
    const int row0 = blockIdx.y * 128;
    const int col0 = blockIdx.x * 128;
    const int sw   = c & 7;

    f32x4 acc[2][4];
#pragma unroll
    for (int m = 0; m < 2; ++m)
#pragma unroll
        for (int n = 0; n < 4; ++n) acc[m][n] = (f32x4){0.f, 0.f, 0.f, 0.f};

    for (int k0 = 0; k0 < K; k0 += 64) {
        __syncthreads();
#pragma unroll
        for (int i = 0; i < 2; ++i) {   // 1024 chunks per matrix / 512 thr
            int idx = tid + i * 512;
            int r = idx >> 3, p = idx & 7;
            int g = p ^ (r & 7);
            gload_lds16(Ag + (size_t)(row0 + r) * K + k0 + g * 8, &As[idx * 8]);
            gload_lds16(Bg + (size_t)(col0 + r) * K + k0 + g * 8, &Bs[idx * 8]);
        }
        __syncthreads();

        h16x8 af[2][2];
#pragma unroll
        for (int m = 0; m < 2; ++m)
#pragma unroll
            for (int kh = 0; kh < 2; ++kh)
                af[m][kh] = *(const h16x8*)&As[(wm + m * 16 + c) * 64 +
                                              ((kh * 4 + quad) ^ sw) * 8];
#pragma unroll
        for (int kh = 0; kh < 2; ++kh)
#pragma unroll
            for (int n = 0; n < 4; ++n) {
                h16x8 bf = *(const h16x8*)&Bs[(wn + n * 16 + c) * 64 +
                                              ((kh * 4 + quad) ^ sw) * 8];
#pragma unroll
                for (int m = 0; m < 2; ++m)
                    acc[m][n] = __builtin_amdgcn_mfma_f32_16x16x32_f16(
                        af[m][kh], bf, acc[m][n], 0, 0, 0);
            }
    }

#pragma unroll
    for (int n = 0; n < 4; ++n) {
        const int col = col0 + wn + n * 16 + c;
        const float bv = bias[col];
        const int h = (col >> 6) & 15, d = col & 63;
#pragma unroll
        for (int m = 0; m < 2; ++m) {
            const int rbase = row0 + wm + m * 16 + quad * 4;
            const int b = rbase >> 11, s0 = rbase & (SEQ - 1);
            const int bh = (b << 4) + h;
            if (col0 < DIM) {
#pragma unroll
                for (int r = 0; r < 4; ++r)
                    Qh[((size_t)bh * SEQ + s0 + r) * 64 + d] =
                        f2h((acc[m][n][r] + bv) * QSCALE);
            } else if (col0 < 2 * DIM) {
#pragma unroll
                for (int r = 0; r < 4; ++r)
                    Kh[((size_t)bh * SEQ + s0 + r) * 64 + d] =
                        f2h(acc[m][n][r] + bv);
            } else {
                uint2 pv = make_uint2(pack2h(acc[m][n][0] + bv, acc[m][n][1] + bv),
                                      pack2h(acc[m][n][2] + bv, acc[m][n][3] + bv));
                *(uint2*)&Vh[((size_t)bh * 64 + d) * SEQ + s0] = pv;
            }
        }
    }
}

// ---------------------------------------------------------------------------
// Out-proj GEMM: C[M,N] = A[M,K] @ B[N,K]^T + bias, fp32 out. 128x128 tile,
// 512 threads = 8 waves (was 256/4: at 256 blocks = 1 block/CU that meant
// 1 wave/SIMD -- zero latency hiding). Now 2 waves/SIMD. K order per output
// element unchanged -> bitwise identical.
// ---------------------------------------------------------------------------
__global__ __launch_bounds__(512)
void gemm_out(const u16* __restrict__ Ag, const u16* __restrict__ Bg,
              const float* __restrict__ bias, float* __restrict__ Cout,
              int M, int N, int K) {
    __shared__ u16 As[128 * 64];
    __shared__ u16 Bs[128 * 64];

    const int tid  = threadIdx.x;
    const int lane = tid & 63;
    const int w    = tid >> 6;          // 0..7
    const int c    = lane & 15;
    const int quad = lane >> 4;
    const int wm   = (w & 3) * 32;
    const int wn   = (w >> 2) * 64;
    const int row0 = blockIdx.y * 128;
    const int col0 = blockIdx.x * 128;
    const int sw   = c & 7;

    f32x4 acc[2][4];
#pragma unroll
    for (int m = 0; m < 2; ++m)
#pragma unroll
        for (int n = 0; n < 4; ++n) acc[m][n] = (f32x4){0.f, 0.f, 0.f, 0.f};

    for (int k0 = 0; k0 < K; k0 += 64) {
        __syncthreads();
#pragma unroll
        for (int i = 0; i < 2; ++i) {
            int idx = tid + i * 512;
            int r = idx >> 3, p = idx & 7;
            int g = p ^ (r & 7);
            gload_lds16(Ag + (size_t)(row0 + r) * K + k0 + g * 8, &As[idx * 8]);
            gload_lds16(Bg + (size_t)(col0 + r) * K + k0 + g * 8, &Bs[idx * 8]);
        }
        __syncthreads();

        h16x8 af[2][2];
#pragma unroll
        for (int m = 0; m < 2; ++m)
#pragma unroll
            for (int kh = 0; kh < 2; ++kh)
                af[m][kh] = *(const h16x8*)&As[(wm + m * 16 + c) * 64 +
                                              ((kh * 4 + quad) ^ sw) * 8];
#pragma unroll
        for (int kh = 0; kh < 2; ++kh)
#pragma unroll
            for (int n = 0; n < 4; ++n) {
                h16x8 bf = *(const h16x8*)&Bs[(wn + n * 16 + c) * 64 +
                                              ((kh * 4 + quad) ^ sw) * 8];
#pragma unroll
                for (int m = 0; m < 2; ++m)
                    acc[m][n] = __builtin_amdgcn_mfma_f32_16x16x32_f16(
                        af[m][kh], bf, acc[m][n], 0, 0, 0);
            }
    }

#pragma unroll
    for (int n = 0; n < 4; ++n) {
        const int col = col0 + wn + n * 16 + c;
        const float bv = bias[col];
#pragma unroll
        for (int m = 0; m < 2; ++m) {
            const int rbase = row0 + wm + m * 16 + quad * 4;
#pragma unroll
            for (int r = 0; r < 4; ++r)
                Cout[(size_t)(rbase + r) * N + col] = acc[m][n][r] + bv;
        }
    }
}

// ---------------------------------------------------------------------------
// Flash attention v11 (proven best: 46.7 us). After 4 occupancy/TLP
// experiments (v9/v10: occ 2x -> +5%; v13/v14: grid-limited; v15: key-split
// didn't co-schedule), conclusion: this kernel is bound by the intra-wave
// MFMA->exp2->pack->MFMA chain + pipe-sum, not wave count. v11 = the local
// optimum: 4 waves (2 q-halves x 2 key-halves), 2-strip ILP, LDS dbuf
// prefetch, in-register P via permlane32_swap, setprio on MFMA clusters.
// ---------------------------------------------------------------------------
__global__ __launch_bounds__(256, 2)
void flash_attn11(const u16* __restrict__ Qg, const u16* __restrict__ Kg,
                  const u16* __restrict__ Vg, u16* __restrict__ aout) {
    __shared__ u16 Qs[128 * 64];        // Q staging, then l-combine (16 KB)
    __shared__ u16 Ks[2][128 * 64];     // [key][d]   (32 KB)
    __shared__ u16 Vt[2][64 * 128];     // [d][key]   (32 KB), then O-combine

    const int tid  = threadIdx.x;
    const int lane = tid & 63;
    const int w    = tid >> 6;          // 0..3
    const int wq   = w & 1;             // q-half (64 rows)
    const int wk   = w >> 1;            // key-half
    const int n32  = lane & 31;         // q column within strip
    const int q5   = lane >> 5;         // 0/1
    const int bh   = blockIdx.y;
    const int q0   = blockIdx.x * 128;

    const u16* Qb = Qg + (size_t)bh * SEQ * 64;
    const u16* Kb = Kg + (size_t)bh * SEQ * 64;
    const u16* Vb = Vg + (size_t)bh * 64 * SEQ;

    // ---- prologue: stage Q + 128-key tile 0 (256 threads: 4 iters each) ----
#pragma unroll
    for (int i = 0; i < 4; ++i) {
        int idx = tid + i * 256;
        int r = idx >> 3, p = idx & 7, g = p ^ (r & 7);
        gload_lds16(Qb + (size_t)(q0 + r) * 64 + g * 8, &Qs[idx * 8]);
    }
#pragma unroll
    for (int i = 0; i < 4; ++i) {
        int idx = tid + i * 256;
        int rk = idx >> 3, pk = idx & 7, gk = pk ^ (rk & 7);
        gload_lds16(Kb + (size_t)rk * 64 + gk * 8, &Ks[0][idx * 8]);
        int rv = idx >> 4, cv = idx & 15, gv = cv ^ (rv & 7);
        gload_lds16(Vb + (size_t)rv * SEQ + gv * 8, &Vt[0][idx * 8]);
    }
    __syncthreads();

    const int qrowA = wq * 64 + n32;    // strip A q row (block-local)
    const int qrowB = qrowA + 32;       // strip B
    const int sw    = n32 & 7;          // == qrowA&7 == qrowB&7 == key/d-row&7
    h16x8 qbA[4], qbB[4];               // Q B-frags, loop-invariant
#pragma unroll
    for (int s = 0; s < 4; ++s) {
        const int ch = ((s * 2 + q5) ^ sw) * 8;
        qbA[s] = *(const h16x8*)&Qs[qrowA * 64 + ch];
        qbB[s] = *(const h16x8*)&Qs[qrowB * 64 + ch];
    }

    float lA = 0.f, lB = 0.f;
    f32x16 oA[2] = {zero16(), zero16()};  // O^T[d-tile][q], strip A (wk half)
    f32x16 oB[2] = {zero16(), zero16()};  // strip B

    for (int kt = 0; kt < SEQ / 128; ++kt) {
        const int cur = kt & 1, nxt = cur ^ 1;

        // ---- stage next 128-key tile (loads fly during compute) ----
        if (kt < SEQ / 128 - 1) {
            const int k1 = (kt + 1) * 128;
#pragma unroll
            for (int i = 0; i < 4; ++i) {
                int idx = tid + i * 256;
                int rk = idx >> 3, pk = idx & 7, gk = pk ^ (rk & 7);
                gload_lds16(Kb + (size_t)(k1 + rk) * 64 + gk * 8, &Ks[nxt][idx * 8]);
                int rv = idx >> 4, cv = idx & 15, gv = cv ^ (rv & 7);
                gload_lds16(Vb + (size_t)rv * SEQ + k1 + gv * 8, &Vt[nxt][idx * 8]);
            }
        }

        // ---- this wave's 64-key subtile x 64 q-rows, P in registers ----
        unsigned xwA[8][2], xwB[8][2];  // packed fp16 P, chunk-major
#pragma unroll
        for (int sub = 0; sub < 2; ++sub) {
            const int kr = wk * 64 + sub * 32 + n32;   // kr&7 == sw
            f32x16 saA = zero16(), saB = zero16();
            __builtin_amdgcn_s_setprio(1);
#pragma unroll
            for (int s = 0; s < 4; ++s) {
                h16x8 ak = *(const h16x8*)&Ks[cur][kr * 64 +
                                                   (((s * 2 + q5) ^ sw) * 8)];
                saA = __builtin_amdgcn_mfma_f32_32x32x16_f16(ak, qbA[s], saA, 0, 0, 0);
                saB = __builtin_amdgcn_mfma_f32_32x32x16_f16(ak, qbB[s], saB, 0, 0, 0);
            }
            __builtin_amdgcn_s_setprio(0);
#pragma unroll
            for (int rr = 0; rr < 4; ++rr) {
                float a0 = __builtin_amdgcn_exp2f(saA[4 * rr + 0]);
                float a1 = __builtin_amdgcn_exp2f(saA[4 * rr + 1]);
                float a2 = __builtin_amdgcn_exp2f(saA[4 * rr + 2]);
                float a3 = __builtin_amdgcn_exp2f(saA[4 * rr + 3]);
                lA += (a0 + a1) + (a2 + a3);
                xwA[sub * 4 + rr][0] = pkrtz(a0, a1);
                xwA[sub * 4 + rr][1] = pkrtz(a2, a3);
                float b0 = __builtin_amdgcn_exp2f(saB[4 * rr + 0]);
                float b1 = __builtin_amdgcn_exp2f(saB[4 * rr + 1]);
                float b2 = __builtin_amdgcn_exp2f(saB[4 * rr + 2]);
                float b3 = __builtin_amdgcn_exp2f(saB[4 * rr + 3]);
                lB += (b0 + b1) + (b2 + b3);
                xwB[sub * 4 + rr][0] = pkrtz(b0, b1);
                xwB[sub * 4 + rr][1] = pkrtz(b2, b3);
            }
        }

        // ---- P^T B-frags via permlane32_swap (no LDS round trip) ----
        h16x8 bpA[4], bpB[4];
#pragma unroll
        for (int s = 0; s < 4; ++s) {
            i32x2 ra = __builtin_amdgcn_permlane32_swap(
                (int)xwA[2 * s][0], (int)xwA[2 * s + 1][0], false, false);
            i32x2 rb = __builtin_amdgcn_permlane32_swap(
                (int)xwA[2 * s][1], (int)xwA[2 * s + 1][1], false, false);
            union { int u[4]; h16x8 h; } fa;
            fa.u[0] = ra[0]; fa.u[1] = rb[0]; fa.u[2] = ra[1]; fa.u[3] = rb[1];
            bpA[s] = fa.h;
            i32x2 rc = __builtin_amdgcn_permlane32_swap(
                (int)xwB[2 * s][0], (int)xwB[2 * s + 1][0], false, false);
            i32x2 rd = __builtin_amdgcn_permlane32_swap(
                (int)xwB[2 * s][1], (int)xwB[2 * s + 1][1], false, false);
            union { int u[4]; h16x8 h; } fb;
            fb.u[0] = rc[0]; fb.u[1] = rd[0]; fb.u[2] = rc[1]; fb.u[3] = rd[1];
            bpB[s] = fb.h;
        }

        // O^T += V^T P^T  (V columns of this wave's key-half; av shared)
        __builtin_amdgcn_s_setprio(1);
#pragma unroll
        for (int dt = 0; dt < 2; ++dt) {
            const int dr = dt * 32 + n32;       // dr&7 == sw
#pragma unroll
            for (int s = 0; s < 4; ++s) {
                h16x8 av = *(const h16x8*)&Vt[cur][dr * 128 +
                                                   ((wk * 8 + ((s * 2 + q5) ^ sw)) * 8)];
                oA[dt] = __builtin_amdgcn_mfma_f32_32x32x16_f16(av, bpA[s], oA[dt], 0, 0, 0);
                oB[dt] = __builtin_amdgcn_mfma_f32_32x32x16_f16(av, bpB[s], oB[dt], 0, 0, 0);
            }
        }
        __builtin_amdgcn_s_setprio(0);

        __syncthreads();   // cur readers done + nxt staged (vmcnt drain)
    }

    // ---- merge q5 halves (intra-wave), then key-halves (cross-wave) ----
    lA += __shfl_xor(lA, 32, 64);
    lB += __shfl_xor(lB, 32, 64);

    float* oc = (float*)Vt;             // 8192 floats, dead after last barrier
    float* lc = (float*)Qs;             // 4096 floats, dead
    const int rowA = (wq * 2 + 0) * 64 + lane;    // per-thread slot, strip A
    const int rowB = (wq * 2 + 1) * 64 + lane;    // strip B (256 rows x 32 fl)
    if (wk == 1) {
#pragma unroll
        for (int dt = 0; dt < 2; ++dt)
#pragma unroll
            for (int i = 0; i < 16; ++i) {
                oc[rowA * 32 + ((dt * 16 + i + lane) & 31)] = oA[dt][i];
                oc[rowB * 32 + ((dt * 16 + i + lane) & 31)] = oB[dt][i];
            }
        lc[rowA] = lA;
        lc[rowB] = lB;
    }
    __syncthreads();
    if (wk == 1) return;
    lA += lc[rowA];
    lB += lc[rowB];
#pragma unroll
    for (int dt = 0; dt < 2; ++dt)
#pragma unroll
        for (int i = 0; i < 16; ++i) {
            oA[dt][i] += oc[rowA * 32 + ((dt * 16 + i + lane) & 31)];
            oB[dt][i] += oc[rowB * 32 + ((dt * 16 + i + lane) & 31)];
        }

    const float invA = 1.f / lA, invB = 1.f / lB;
    const int b = bh >> 4, h = bh & 15;
    const size_t roA = (size_t)(b * SEQ + q0 + qrowA) * DIM + h * HDIM;
    const size_t roB = (size_t)(b * SEQ + q0 + qrowB) * DIM + h * HDIM;
#pragma unroll
    for (int dt = 0; dt < 2; ++dt) {
#pragma unroll
        for (int rq = 0; rq < 4; ++rq) {
            const int d = dt * 32 + 8 * rq + 4 * q5;
            *(uint2*)&aout[roA + d] = make_uint2(
                pkrtz(oA[dt][4 * rq + 0] * invA, oA[dt][4 * rq + 1] * invA),
                pkrtz(oA[dt][4 * rq + 2] * invA, oA[dt][4 * rq + 3] * invA));
            *(uint2*)&aout[roB + d] = make_uint2(
                pkrtz(oB[dt][4 * rq + 0] * invB, oB[dt][4 * rq + 1] * invB),
                pkrtz(oB[dt][4 * rq + 2] * invB, oB[dt][4 * rq + 3] * invB));
        }
    }
}

// ---------------------------------------------------------------------------
extern "C" void kernel_launch(void* const* d_in, const int* in_sizes, int n_in,
                              void* d_out, int out_size, void* d_ws, size_t ws_size,
                              hipStream_t stream) {
    (void)in_sizes; (void)n_in; (void)out_size; (void)ws_size;
    const float* x    = (const float*)d_in[0];   // [4096,1024]
    const float* wqkv = (const float*)d_in[1];   // [1024,3072]
    const float* bqkv = (const float*)d_in[2];   // [3072]
    const float* wo   = (const float*)d_in[3];   // [1024,1024]
    const float* bo   = (const float*)d_in[4];   // [1024]
    float* out = (float*)d_out;                  // [4096,1024] fp32

    // workspace (48 MB)
    const size_t HB = (size_t)BATCH * NHEAD * SEQ * HDIM;   // 4M elems
    u16* Qh  = (u16*)d_ws;                       // [32][2048][64]
    u16* Kh  = Qh + HB;                          // [32][2048][64]
    u16* Vh  = Kh + HB;                          // [32][64][2048]
    u16* ao  = Vh + HB;                          // attn out fp16 [4096][1024]
    u16* wqT = ao + (size_t)TOK * DIM;           // wqkv^T fp16 [3072][1024]
    u16* woT = wqT + (size_t)3 * DIM * DIM;      // wo^T fp16 [1024][1024]
    u16* xh  = woT + (size_t)DIM * DIM;          // x fp16 [4096][1024]

    // 1) fused converts (single launch)
    fused_cvt<<<8192, 256, 0, stream>>>(x, xh, wqkv, wqT, wo, woT);
    // 2) qkv GEMM with per-head re-layout epilogue (512 thr, 6 waves/SIMD)
    gemm_qkv<<<dim3(3 * DIM / 128, TOK / 128), 512, 0, stream>>>(
        xh, wqT, bqkv, Qh, Kh, Vh, DIM, 3 * DIM);
    // 3) attention -> fp16 out (v11 proven best)
    flash_attn11<<<dim3(SEQ / 128, BATCH * NHEAD), 256, 0, stream>>>(
        Qh, Kh, Vh, ao);
    // 4) out = attn @ wo + bo (fp32 out, 128x128 tile, 512 thr)
    gemm_out<<<dim3(DIM / 128, TOK / 128), 512, 0, stream>>>(
        ao, woT, bo, out, TOK, DIM, DIM);
}